// Round 7
// baseline (223.232 us; speedup 1.0000x reference)
//
#include <hip/hip_runtime.h>
#include <hip/hip_bf16.h>
#include <stdint.h>

typedef __bf16 bf16x8 __attribute__((ext_vector_type(8)));
typedef float  f32x4  __attribute__((ext_vector_type(4)));
typedef unsigned short ushort8v __attribute__((ext_vector_type(8)));

__device__ __forceinline__ unsigned short f2bf(float f) {
  unsigned int u = __float_as_uint(f);
  u += 0x7FFF + ((u >> 16) & 1);          // round-to-nearest-even
  return (unsigned short)(u >> 16);
}
__device__ __forceinline__ float bf2f(unsigned short h) {
  return __uint_as_float(((unsigned int)h) << 16);
}

#define GLOAD_LDS(gptr, ldsptr)                                                     \
  __builtin_amdgcn_global_load_lds(                                                 \
      (const __attribute__((address_space(1))) unsigned int*)(gptr),                \
      (__attribute__((address_space(3))) unsigned int*)(ldsptr), 16, 0, 0)

#define BM 128
#define BN 128
#define BK 32

// ===== fused convert+projection: Out_z = cvt_bf16(X_z) * W_z^T, X fp32 =====
// z=0: qh, z=1: kh (bf16 [8192,1024]); z=2: vhT (bf16 [b][col][l]).
// A reg-staged fp32 -> cvt bf16 -> swizzled ds_write (2-buf LDS, T14 split);
// B (bf16 weights) via global_load_lds pre-swizzled source (3-buf).
// One barrier per K-step; counted vmcnt(6) (A kt+2 4 loads + B kt+2 2 loads in flight).
__global__ __launch_bounds__(256, 3) void proj_fused(
    const float* __restrict__ Aq, const float* __restrict__ Ak, const float* __restrict__ Av,
    const unsigned short* __restrict__ W,
    unsigned short* __restrict__ Out)
{
  const int K = 1024, N = 1024;
  // m204 bijective XCD chunk swizzle (nwg=512, 512%8==0)
  const int nwg = gridDim.x, orig = blockIdx.x;
  const int qq = nwg >> 3, rr = nwg & 7, xc = orig & 7, oo = orig >> 3;
  const int wg = (xc < rr ? xc * (qq + 1) : rr * (qq + 1) + (xc - rr) * qq) + oo;
  const int mt = wg >> 3, nt = wg & 7;
  const int z = blockIdx.y;
  const float* A = (z == 0) ? Aq : (z == 1) ? Ak : Av;
  const unsigned short* B = W + (long)z * (1024 * 1024);

  __shared__ __align__(16) unsigned short As[2][128 * 32];  // 16 KB
  __shared__ __align__(16) unsigned short Bs[3][128 * 32];  // 24 KB

  const int tid = threadIdx.x, wave = tid >> 6, lane = tid & 63;
  const int wr = wave >> 1, wc = wave & 1;

  f32x4 acc[4][4];
#pragma unroll
  for (int i = 0; i < 4; ++i)
#pragma unroll
    for (int j = 0; j < 4; ++j) acc[i][j] = (f32x4){0.f, 0.f, 0.f, 0.f};

  // ---- A staging geometry: thread t -> row t>>1, 16 floats at colhalf (t&1)*16 ----
  const int arow = tid >> 1;
  const int acs  = (tid & 1) * 2;            // first 16B (8-elem) slot: 0 or 2
  const int asw  = (arow >> 1) & 3;          // row swizzle (matches read side)
  const float* abase = A + (long)(mt * 128 + arow) * K + acs * 8;
  unsigned short* wp00 = &As[0][arow * 32 + ((acs    ) ^ asw) * 8];
  unsigned short* wp01 = &As[0][arow * 32 + ((acs + 1) ^ asw) * 8];
  unsigned short* wp10 = &As[1][arow * 32 + ((acs    ) ^ asw) * 8];
  unsigned short* wp11 = &As[1][arow * 32 + ((acs + 1) ^ asw) * 8];

  // ---- B staging: gload_lds, pre-swizzled source (rule 21) ----
  const int r0 = tid >> 2, s0 = tid & 3;
  const int c0 = ((s0 ^ ((r0 >> 1) & 3)) << 3);
  const int r1 = r0 + 64;
  const int c1 = ((s0 ^ ((r1 >> 1) & 3)) << 3);
  const long boff0 = (long)(nt * 128 + r0) * K + c0;
  const long boff1 = (long)(nt * 128 + r1) * K + c1;
  const unsigned ldsw = wave * 1024;

  float4 rAe0, rAe1, rAe2, rAe3, rAo0, rAo1, rAo2, rAo3;

#define LOADAE(kt) do { const float4* p_ = (const float4*)(abase + (kt) * 32);      \
    rAe0 = p_[0]; rAe1 = p_[1]; rAe2 = p_[2]; rAe3 = p_[3]; } while (0)
#define LOADAO(kt) do { const float4* p_ = (const float4*)(abase + (kt) * 32);      \
    rAo0 = p_[0]; rAo1 = p_[1]; rAo2 = p_[2]; rAo3 = p_[3]; } while (0)
#define BSTAGE(m, kt) do {                                                          \
    GLOAD_LDS(B + boff0 + (kt) * 32, (char*)&Bs[m][0]    + ldsw);                   \
    GLOAD_LDS(B + boff1 + (kt) * 32, (char*)&Bs[m][2048] + ldsw); } while (0)
#define CVTW(bi, a0, a1, a2, a3) do {                                               \
    ushort8v h0_, h1_;                                                              \
    h0_[0]=f2bf(a0.x); h0_[1]=f2bf(a0.y); h0_[2]=f2bf(a0.z); h0_[3]=f2bf(a0.w);     \
    h0_[4]=f2bf(a1.x); h0_[5]=f2bf(a1.y); h0_[6]=f2bf(a1.z); h0_[7]=f2bf(a1.w);     \
    h1_[0]=f2bf(a2.x); h1_[1]=f2bf(a2.y); h1_[2]=f2bf(a2.z); h1_[3]=f2bf(a2.w);     \
    h1_[4]=f2bf(a3.x); h1_[5]=f2bf(a3.y); h1_[6]=f2bf(a3.z); h1_[7]=f2bf(a3.w);     \
    if (bi) { *(ushort8v*)wp10 = h0_; *(ushort8v*)wp11 = h1_; }                     \
    else    { *(ushort8v*)wp00 = h0_; *(ushort8v*)wp01 = h1_; } } while (0)
#define COMPUTE(abuf, bmod) do {                                                    \
    bf16x8 af_[4], bf_[4];                                                          \
    _Pragma("unroll")                                                               \
    for (int i_ = 0; i_ < 4; ++i_) {                                                \
      const int ar_ = wr * 64 + i_ * 16 + (lane & 15);                              \
      const int as_ = ((lane >> 4) ^ ((ar_ >> 1) & 3)) << 3;                        \
      af_[i_] = *(const bf16x8*)&As[abuf][ar_ * 32 + as_];                          \
      const int br_ = wc * 64 + i_ * 16 + (lane & 15);                              \
      const int bs_ = ((lane >> 4) ^ ((br_ >> 1) & 3)) << 3;                        \
      bf_[i_] = *(const bf16x8*)&Bs[bmod][br_ * 32 + bs_]; }                        \
    _Pragma("unroll")                                                               \
    for (int mi_ = 0; mi_ < 4; ++mi_)                                               \
    _Pragma("unroll")                                                               \
      for (int ni_ = 0; ni_ < 4; ++ni_)                                             \
        acc[mi_][ni_] = __builtin_amdgcn_mfma_f32_16x16x32_bf16(                    \
            af_[mi_], bf_[ni_], acc[mi_][ni_], 0, 0, 0); } while (0)

  // ---- prologue: A(0),A(1) -> regs; B(0),B(1) -> LDS; write As[0] ----
  LOADAE(0); LOADAO(1);
  BSTAGE(0, 0); BSTAGE(1, 1);
  asm volatile("s_waitcnt vmcnt(2)" ::: "memory");   // rAe,rAo,B(0) landed; B(1) in flight
  CVTW(0, rAe0, rAe1, rAe2, rAe3);
  asm volatile("s_waitcnt lgkmcnt(0)" ::: "memory");
  __builtin_amdgcn_s_barrier();
  asm volatile("" ::: "memory");

  // ---- main loop: K-steps in pairs (kiters=32), last pair peeled ----
  int m0 = 0;
  for (int kt = 0; kt < 30; kt += 2) {
    const int m1 = (m0 + 1) % 3, m2 = (m0 + 2) % 3;
    // even step kt: compute As[0] x Bs[m0]; prefetch kt+2; write A(kt+1)
    LOADAE(kt + 2);
    BSTAGE(m2, kt + 2);
    COMPUTE(0, m0);
    asm volatile("s_waitcnt vmcnt(6)" ::: "memory");  // A(kt+1),B(kt+1) landed
    CVTW(1, rAo0, rAo1, rAo2, rAo3);
    asm volatile("s_waitcnt lgkmcnt(0)" ::: "memory");
    __builtin_amdgcn_s_barrier();
    asm volatile("" ::: "memory");
    // odd step kt+1: compute As[1] x Bs[m1]; prefetch kt+3; write A(kt+2)
    LOADAO(kt + 3);
    BSTAGE(m0, kt + 3);                               // (kt+3)%3 == m0
    COMPUTE(1, m1);
    asm volatile("s_waitcnt vmcnt(6)" ::: "memory");  // A(kt+2),B(kt+2) landed
    CVTW(0, rAe0, rAe1, rAe2, rAe3);
    asm volatile("s_waitcnt lgkmcnt(0)" ::: "memory");
    __builtin_amdgcn_s_barrier();
    asm volatile("" ::: "memory");
    m0 = m2;
  }
  // peeled tail: kt=30 (m0 = 30%3 = 0)
  COMPUTE(0, 0);
  asm volatile("s_waitcnt vmcnt(0)" ::: "memory");    // A(31),B(31) landed
  CVTW(1, rAo0, rAo1, rAo2, rAo3);
  asm volatile("s_waitcnt lgkmcnt(0)" ::: "memory");
  __builtin_amdgcn_s_barrier();
  asm volatile("" ::: "memory");
  COMPUTE(1, 1);                                      // kt=31: Bs[31%3=1]

#undef LOADAE
#undef LOADAO
#undef BSTAGE
#undef CVTW
#undef COMPUTE

  // ---- epilogue ----
  const int rb = mt * 128 + wr * 64;
  const int cb = nt * 128 + wc * 64;
  if (z < 2) {
    unsigned short* Cb = Out + (long)z * (8192L * 1024);
#pragma unroll
    for (int mi = 0; mi < 4; ++mi)
#pragma unroll
      for (int ni = 0; ni < 4; ++ni) {
        const int row0 = rb + mi * 16 + ((lane >> 4) << 2);
        const int col  = cb + ni * 16 + (lane & 15);
#pragma unroll
        for (int j = 0; j < 4; ++j)
          Cb[(long)(row0 + j) * N + col] = f2bf(acc[mi][ni][j]);
      }
  } else {
    unsigned short* Cb = Out + 2L * (8192L * 1024);
#pragma unroll
    for (int mi = 0; mi < 4; ++mi)
#pragma unroll
      for (int ni = 0; ni < 4; ++ni) {
        const int row0 = rb + mi * 16 + ((lane >> 4) << 2);
        const int col  = cb + ni * 16 + (lane & 15);
#pragma unroll
        for (int j = 0; j < 4; ++j) {
          const int row = row0 + j;
          const int b = row >> 11, l = row & 2047;
          Cb[((long)b * N + col) * 2048 + l] = f2bf(acc[mi][ni][j]);
        }
      }
  }
}

// ============ 128x128 3-buf GEMM: C = A[M,K] * B[N,K]^T (bf16 in) ============
// mode 0: C bf16 [M,N] * scale; mode 2: C fp32 [M,N] * scale
// tilemap 0: m204 XCD chunk swizzle (uniform grids)
// tilemap 1: triangular decode -> (mt,nt), nt<=mt (causal S)
// tilemap 2: paired causal map mt={c,15-c}, nt=orig>>4, + K-limit (PV)
__global__ __launch_bounds__(256, 3) void gemm_bt(
    const unsigned short* __restrict__ A,
    const unsigned short* __restrict__ B,
    void* __restrict__ C,
    int M, int N, int K, int ntiles,
    long sAz, long sBz, long sCz,
    int mode, int tilemap, float scale)
{
  int mt, nt;
  const int orig = blockIdx.x;
  if (tilemap == 0) {
    const int nwg = gridDim.x;
    const int qq = nwg >> 3, rr = nwg & 7, xc = orig & 7, oo = orig >> 3;
    const int wg = (xc < rr ? xc * (qq + 1) : rr * (qq + 1) + (xc - rr) * qq) + oo;
    mt = wg / ntiles; nt = wg % ntiles;
  } else if (tilemap == 1) {
    mt = (int)((sqrtf(8.f * orig + 1.f) - 1.f) * 0.5f);
    int base = mt * (mt + 1) / 2;
    if (orig < base) { mt--; base = mt * (mt + 1) / 2; }
    else if (orig >= base + mt + 1) { mt++; base = mt * (mt + 1) / 2; }
    nt = orig - base;
  } else {
    const int c = orig & 15;
    mt = (c & 8) ? (15 - (c & 7)) : c;
    nt = orig >> 4;
  }
  const int z = blockIdx.y;

  A += sAz * (long)z;
  B += sBz * (long)z;

  __shared__ __align__(16) unsigned short As[3][BM * BK];
  __shared__ __align__(16) unsigned short Bs[3][BN * BK];

  const int tid  = threadIdx.x;
  const int wave = tid >> 6;
  const int lane = tid & 63;
  const int wr = wave >> 1, wc = wave & 1;

  f32x4 acc[4][4];
#pragma unroll
  for (int i = 0; i < 4; ++i)
#pragma unroll
    for (int j = 0; j < 4; ++j) acc[i][j] = (f32x4){0.f, 0.f, 0.f, 0.f};

  int kiters = K / BK;
  if (tilemap == 2) { const int kl = (mt + 1) * (BM / BK); if (kl < kiters) kiters = kl; }

  const int r0 = tid >> 2, s0 = tid & 3;
  const int c0 = ((s0 ^ ((r0 >> 1) & 3)) << 3);
  const int r1 = r0 + 64;
  const int c1 = ((s0 ^ ((r1 >> 1) & 3)) << 3);
  const long aoff0 = (long)(mt * BM + r0) * K + c0;
  const long aoff1 = (long)(mt * BM + r1) * K + c1;
  const long boff0 = (long)(nt * BN + r0) * K + c0;
  const long boff1 = (long)(nt * BN + r1) * K + c1;
  const unsigned ldsw = wave * 1024;

#define STAGE(bi, k0)                                                     \
  do {                                                                    \
    GLOAD_LDS(A + aoff0 + (k0), (char*)&As[bi][0]    + ldsw);             \
    GLOAD_LDS(A + aoff1 + (k0), (char*)&As[bi][2048] + ldsw);             \
    GLOAD_LDS(B + boff0 + (k0), (char*)&Bs[bi][0]    + ldsw);             \
    GLOAD_LDS(B + boff1 + (k0), (char*)&Bs[bi][2048] + ldsw);             \
  } while (0)

  STAGE(0, 0);
  if (kiters > 1) STAGE(1, BK);

  int cur = 0;
  for (int kt = 0; kt < kiters; ++kt) {
    const int rem = kiters - 1 - kt;
    if (rem >= 2) {
      int sb = cur + 2; if (sb >= 3) sb -= 3;
      STAGE(sb, (kt + 2) * BK);
      asm volatile("s_waitcnt vmcnt(8)" ::: "memory");
    } else if (rem == 1) {
      asm volatile("s_waitcnt vmcnt(4)" ::: "memory");
    } else {
      asm volatile("s_waitcnt vmcnt(0)" ::: "memory");
    }
    __builtin_amdgcn_s_barrier();
    asm volatile("" ::: "memory");

    bf16x8 af[4], bfr[4];
#pragma unroll
    for (int i = 0; i < 4; ++i) {
      const int ar = wr * 64 + i * 16 + (lane & 15);
      const int as = ((lane >> 4) ^ ((ar >> 1) & 3)) << 3;
      af[i] = *(const bf16x8*)&As[cur][ar * BK + as];
      const int br = wc * 64 + i * 16 + (lane & 15);
      const int bs = ((lane >> 4) ^ ((br >> 1) & 3)) << 3;
      bfr[i] = *(const bf16x8*)&Bs[cur][br * BK + bs];
    }
#pragma unroll
    for (int mi = 0; mi < 4; ++mi)
#pragma unroll
      for (int ni = 0; ni < 4; ++ni)
        acc[mi][ni] = __builtin_amdgcn_mfma_f32_16x16x32_bf16(af[mi], bfr[ni], acc[mi][ni], 0, 0, 0);

    asm volatile("" ::: "memory");
    __builtin_amdgcn_s_barrier();
    cur = (cur == 2) ? 0 : cur + 1;
  }
#undef STAGE

  const int rb = mt * BM + wr * 64;
  const int cb = nt * BN + wc * 64;

  if (mode == 0) {
    unsigned short* Cb = (unsigned short*)C + sCz * (long)z;
#pragma unroll
    for (int mi = 0; mi < 4; ++mi)
#pragma unroll
      for (int ni = 0; ni < 4; ++ni) {
        const int row0 = rb + mi * 16 + ((lane >> 4) << 2);
        const int col  = cb + ni * 16 + (lane & 15);
#pragma unroll
        for (int j = 0; j < 4; ++j)
          Cb[(long)(row0 + j) * N + col] = f2bf(acc[mi][ni][j] * scale);
      }
  } else {
    float* Cf = (float*)C + sCz * (long)z;
#pragma unroll
    for (int mi = 0; mi < 4; ++mi)
#pragma unroll
      for (int ni = 0; ni < 4; ++ni) {
        const int row0 = rb + mi * 16 + ((lane >> 4) << 2);
        const int col  = cb + ni * 16 + (lane & 15);
#pragma unroll
        for (int j = 0; j < 4; ++j)
          Cf[(long)(row0 + j) * N + col] = acc[mi][ni][j] * scale;
      }
  }
}

// single-pass causal row softmax on bf16 S, bounded at the 128-tile ceiling.
__global__ __launch_bounds__(256) void softmax_causal(
    const unsigned short* __restrict__ S, unsigned short* __restrict__ P)
{
  const int r = blockIdx.x;              // 0..B*L-1
  const int b = r >> 11, q = r & 2047;
  const unsigned short* srow = S + ((long)b * 2048 + q) * 2048;
  unsigned short* prow = P + ((long)b * 2048 + q) * 2048;
  const int len = q + 1;
  const int lenceil = ((q >> 7) + 1) << 7;   // PV reads exactly this many cols
  const int tid = threadIdx.x, lane = tid & 63, wave = tid >> 6;
  const int base = tid * 8;
  const bool active = base < lenceil;
  __shared__ float red[8];

  float vv[8];
#pragma unroll
  for (int i = 0; i < 8; ++i) vv[i] = -3.4e38f;
  if (active) {
    ushort8v xv = *(const ushort8v*)(srow + base);
#pragma unroll
    for (int i = 0; i < 8; ++i) vv[i] = bf2f(xv[i]);
  }

  float m = -3.4e38f;
#pragma unroll
  for (int i = 0; i < 8; ++i) if (base + i < len) m = fmaxf(m, vv[i]);
#pragma unroll
  for (int o = 32; o; o >>= 1) m = fmaxf(m, __shfl_xor(m, o));
  if (lane == 0) red[wave] = m;
  __syncthreads();
  m = fmaxf(fmaxf(red[0], red[1]), fmaxf(red[2], red[3]));

  float p[8], s = 0.f;
#pragma unroll
  for (int i = 0; i < 8; ++i) {
    p[i] = (base + i < len) ? __expf(vv[i] - m) : 0.f;
    s += p[i];
  }
#pragma unroll
  for (int o = 32; o; o >>= 1) s += __shfl_xor(s, o);
  if (lane == 0) red[4 + wave] = s;
  __syncthreads();
  s = (red[4] + red[5]) + (red[6] + red[7]);
  const float inv = 1.f / s;

  if (active) {
    ushort8v o16;
#pragma unroll
    for (int i = 0; i < 8; ++i) o16[i] = f2bf(p[i] * inv);
    *(ushort8v*)(prow + base) = o16;
  }
}

// weights-only fp32 -> bf16 (RNE)
__global__ __launch_bounds__(256) void convert_w(
    const float* __restrict__ wq, const float* __restrict__ wk,
    const float* __restrict__ wv, const float* __restrict__ wp,
    unsigned short* __restrict__ wb)
{
  const long NV = 262144;                 // float4 per weight
  for (long i = (long)blockIdx.x * 256 + threadIdx.x; i < 4 * NV;
       i += (long)gridDim.x * 256) {
    const int seg = (int)(i >> 18);
    const long off = i & (NV - 1);
    const float* src = (seg == 0) ? wq : (seg == 1) ? wk : (seg == 2) ? wv : wp;
    float4 x = ((const float4*)src)[off];
    ushort4 o;
    o.x = f2bf(x.x); o.y = f2bf(x.y); o.z = f2bf(x.z); o.w = f2bf(x.w);
    ((ushort4*)(wb + (long)seg * 1048576))[off] = o;
  }
}

extern "C" void kernel_launch(void* const* d_in, const int* in_sizes, int n_in,
                              void* d_out, int out_size, void* d_ws, size_t ws_size,
                              hipStream_t stream) {
  const float* q  = (const float*)d_in[0];
  const float* k  = (const float*)d_in[1];
  const float* v  = (const float*)d_in[2];
  const float* Wq = (const float*)d_in[3];
  const float* Wk = (const float*)d_in[4];
  const float* Wv = (const float*)d_in[5];
  const float* Wp = (const float*)d_in[6];
  float* out = (float*)d_out;

  const long D  = 1024;
  const long L  = 2048;
  const long ND = 8192 * D;
  const long NS = 4L * L * L;

  char* ws = (char*)d_ws;
  unsigned short* qh  = (unsigned short*)ws;           // 16 MB (z=0)
  unsigned short* kh  = qh  + ND;                      // 16 MB (z=1)
  unsigned short* vhT = kh  + ND;                      // 16 MB (z=2, transposed)
  unsigned short* P   = vhT + ND;                      // 32 MB
  unsigned short* ybf = P   + NS;                      // 16 MB
  unsigned short* wbf = ybf + ND;                      // 8 MB (4 weights)
  unsigned short* S   = wbf + 4L * D * D;              // 32 MB (bf16)

  // 1) convert weights to bf16
  convert_w<<<1024, 256, 0, stream>>>(Wq, Wk, Wv, Wp, wbf);

  // 2) fused convert+projections: qh, kh, vhT directly from fp32 q,k,v
  proj_fused<<<dim3(512, 3), 256, 0, stream>>>(q, k, v, wbf, qh);

  // 3) S = qh * kh^T * 0.125 (bf16 out) — triangular tile enumeration (136 tiles)
  gemm_bt<<<dim3(136, 4), 256, 0, stream>>>(qh, kh, S,
      2048, 2048, 1024, 16, L * D, L * D, L * L, 0, 1, 0.125f);

  // 4) causal softmax (bf16 in/out, bounded at 128-tile ceiling)
  softmax_causal<<<8192, 256, 0, stream>>>(S, P);

  // 5) Y = P * vh (paired XCD map + K-limit)
  gemm_bt<<<dim3(128, 4), 256, 0, stream>>>(P, vhT, ybf,
      2048, 1024, 2048, 8, L * L, D * L, L * D, 0, 2, 1.0f);

  // 6) out = Y * Wproj^T (fp32)
  gemm_bt<<<dim3(512, 1), 256, 0, stream>>>(ybf, wbf + 3 * D * D, out,
      8192, 1024, 1024, 8, 0, 0, 0, 2, 0, 1.0f);
}